// Round 7
// baseline (674.271 us; speedup 1.0000x reference)
//
#include <hip/hip_runtime.h>
#include <hip/hip_bf16.h>
#include <stdint.h>

#define M_TOTAL 16384
#define N_TOTAL 4096
#define K_TOTAL 4096
#define NT (K_TOTAL / 32)

typedef __attribute__((ext_vector_type(8))) short bf16x8;
typedef __attribute__((ext_vector_type(4))) float f32x4;

__device__ __forceinline__ void gload_lds16(const void* g, void* l) {
    __builtin_amdgcn_global_load_lds(
        (const __attribute__((address_space(1))) uint32_t*)g,
        (__attribute__((address_space(3))) uint32_t*)l, 16, 0, 0);
}

// ---------------------------------------------------------------------------
// Kernel 0: X f32 -> bf16 (134 MB, L3-resident afterwards).
// ---------------------------------------------------------------------------
__global__ __launch_bounds__(256) void k_convX(const float* __restrict__ X,
                                               __hip_bfloat16* __restrict__ Xb) {
    size_t t = (size_t)blockIdx.x * 256 + threadIdx.x;
    const float* p = X + t * 8;
    float4 a = *(const float4*)p;
    float4 b = *(const float4*)(p + 4);
    __hip_bfloat162 o[4] = {
        __float22bfloat162_rn(make_float2(a.x, a.y)),
        __float22bfloat162_rn(make_float2(a.z, a.w)),
        __float22bfloat162_rn(make_float2(b.x, b.y)),
        __float22bfloat162_rn(make_float2(b.z, b.w))};
    *(int4*)(Xb + t * 8) = *(int4*)&o[0];
}

// ---------------------------------------------------------------------------
// Kernel 1: packed int4 -> bf16 W[N][K]. word j of row n: k=2j lo nibble,
// k=2j+1 hi nibble; codes 0..15 -> -8..7, scale[n][k/32] (f32).
// ---------------------------------------------------------------------------
__global__ __launch_bounds__(256) void k_dequant(const int* __restrict__ pw,
                                                 const float* __restrict__ sc,
                                                 __hip_bfloat16* __restrict__ W) {
    int t = blockIdx.x * 256 + threadIdx.x;
    int row = t >> 8;
    int w0 = (t & 255) << 3;
    const int* p = pw + (size_t)row * 2048 + w0;
    int4 q0 = *(const int4*)p;
    int4 q1 = *(const int4*)(p + 4);
    float s = sc[row * 128 + (w0 >> 4)];
    float ns8 = -8.0f * s;
    int w[8] = {q0.x, q0.y, q0.z, q0.w, q1.x, q1.y, q1.z, q1.w};
    __hip_bfloat162 o[8];
#pragma unroll
    for (int i = 0; i < 8; ++i) {
        float lo = fmaf((float)(w[i] & 15), s, ns8);
        float hi = fmaf((float)(w[i] >> 4), s, ns8);
        o[i] = __float22bfloat162_rn(make_float2(lo, hi));
    }
    __hip_bfloat16* dst = W + (size_t)row * 4096 + w0 * 2;
    *(int4*)dst = *(int4*)&o[0];
    *(int4*)(dst + 8) = *(int4*)&o[4];
}

// ---------------------------------------------------------------------------
// Kernel 2 (tier A): 256x256 tile, BK=32, ring-4 LDS, 512 thr (8 waves 2Mx4N),
// per-wave 128x64 = 8x4 frags of mfma 16x16x32. ONE barrier per K-tile.
// Cross-tile register prefetch: frags for tile kt+1 (A-half + B) stream in
// DURING tile kt's 32 MFMA; current tile's second A-half (a2) read in-region
// (its wait hides under the first 16 MFMA). Counted vmcnt(8), never 0 in
// steady state. Conflict-free LDS layout (round-6 verified, conflicts = 0):
// 16B slot s = chunk*8 + row%8 within each 8-row x 64B group; global source
// address carries the permutation, LDS dest stays linear.
// ---------------------------------------------------------------------------
__global__ __launch_bounds__(512, 2) void k_gemm4(const __hip_bfloat16* __restrict__ Xb,
                                                  const __hip_bfloat16* __restrict__ Wb,
                                                  float* __restrict__ out) {
    __shared__ __align__(16) short L[4][2][8192];   // 4 bufs x {A,B} x 16 KiB

    int bid = blockIdx.x;
    int swz = (bid & 7) * 128 + (bid >> 3);         // XCD-bijective (1024 % 8 == 0)
    int bn = swz & 15, bm = swz >> 4;               // N fastest: 16 blocks share A panel
    int m0 = bm * 256, n0 = bn * 256;
    int t = threadIdx.x, lane = t & 63, wv = t >> 6;
    int wm = wv >> 2, wn = wv & 3;

    // staging: slot t -> global (row (t>>5)*8+(t&7), chunk (t>>3)&3); +512 -> +128 rows
    int srow = (t >> 5) * 8 + (t & 7);
    int schk = (t >> 3) & 3;
    const __hip_bfloat16* gA0 = Xb + (size_t)(m0 + srow) * K_TOTAL + schk * 8;
    const __hip_bfloat16* gA1 = gA0 + (size_t)128 * K_TOTAL;
    const __hip_bfloat16* gB0 = Wb + (size_t)(n0 + srow) * K_TOTAL + schk * 8;
    const __hip_bfloat16* gB1 = gB0 + (size_t)128 * K_TOTAL;

    // frag-read lane offset (shorts): row r=R+(lane&15), chunk c=lane>>4
    int offL = ((lane & 15) >> 3) * 256 + ((lane >> 4) * 8 + (lane & 7)) * 8;

    f32x4 acc[8][4];
#pragma unroll
    for (int f = 0; f < 8; ++f)
#pragma unroll
        for (int j = 0; j < 4; ++j) acc[f][j] = (f32x4)(0.0f);

    // ---- prologue: stage tiles 0,1,2; publish tile 0; preload its A/B frags ----
#pragma unroll
    for (int tt = 0; tt < 3; ++tt) {
        gload_lds16(gA0 + tt * 32, &L[tt][0][t * 8]);
        gload_lds16(gA1 + tt * 32, &L[tt][0][4096 + t * 8]);
        gload_lds16(gB0 + tt * 32, &L[tt][1][t * 8]);
        gload_lds16(gB1 + tt * 32, &L[tt][1][4096 + t * 8]);
    }
    asm volatile("s_waitcnt vmcnt(8)" ::: "memory");
    __builtin_amdgcn_s_barrier();

    bf16x8 A0[4], B0[4], A1[4], B1[4];   // double-buffered frag sets (static names)
#pragma unroll
    for (int f = 0; f < 4; ++f) {
        A0[f] = *(const bf16x8*)&L[0][0][(wm * 128 + f * 16) * 32 + offL];
        B0[f] = *(const bf16x8*)&L[0][1][(wn * 64 + f * 16) * 32 + offL];
    }

    // BODY: one K-tile. CA/CB = current frags (ready); NA/NB filled for kt+1.
#define BODY(KT, CA, CB, NA, NB)                                                   \
    {                                                                              \
        const int kt_ = (KT);                                                      \
        if (kt_ + 3 < NT) {                                                        \
            const int bp = (kt_ + 3) & 3;                                          \
            const int pko = (kt_ + 3) * 32;                                        \
            gload_lds16(gA0 + pko, &L[bp][0][t * 8]);                              \
            gload_lds16(gA1 + pko, &L[bp][0][4096 + t * 8]);                       \
            gload_lds16(gB0 + pko, &L[bp][1][t * 8]);                              \
            gload_lds16(gB1 + pko, &L[bp][1][4096 + t * 8]);                       \
        }                                                                          \
        if (kt_ < NT - 1) {                                                        \
            if (kt_ <= NT - 4)      asm volatile("s_waitcnt vmcnt(8)" ::: "memory"); \
            else if (kt_ == NT - 3) asm volatile("s_waitcnt vmcnt(4)" ::: "memory"); \
            else                    asm volatile("s_waitcnt vmcnt(0)" ::: "memory"); \
            __builtin_amdgcn_s_barrier();                                          \
        }                                                                          \
        /* current tile's second A-half: wait hides under first MFMA block */      \
        bf16x8 a2_[4];                                                             \
        const short* LAc_ = &L[kt_ & 3][0][0];                                     \
        _Pragma("unroll")                                                          \
        for (int f = 0; f < 4; ++f)                                                \
            a2_[f] = *(const bf16x8*)&LAc_[(wm * 128 + 64 + f * 16) * 32 + offL];  \
        if (kt_ < NT - 1) {                                                        \
            const short* LAn_ = &L[(kt_ + 1) & 3][0][0];                           \
            const short* LBn_ = &L[(kt_ + 1) & 3][1][0];                           \
            _Pragma("unroll")                                                      \
            for (int f = 0; f < 4; ++f) {                                          \
                NA[f] = *(const bf16x8*)&LAn_[(wm * 128 + f * 16) * 32 + offL];    \
                NB[f] = *(const bf16x8*)&LBn_[(wn * 64 + f * 16) * 32 + offL];     \
            }                                                                      \
        }                                                                          \
        __builtin_amdgcn_s_setprio(1);                                             \
        _Pragma("unroll")                                                          \
        for (int f = 0; f < 4; ++f)                                                \
            _Pragma("unroll")                                                      \
            for (int j = 0; j < 4; ++j)                                            \
                acc[f][j] = __builtin_amdgcn_mfma_f32_16x16x32_bf16(CA[f], CB[j], acc[f][j], 0, 0, 0); \
        _Pragma("unroll")                                                          \
        for (int f = 0; f < 4; ++f)                                                \
            _Pragma("unroll")                                                      \
            for (int j = 0; j < 4; ++j)                                            \
                acc[4 + f][j] = __builtin_amdgcn_mfma_f32_16x16x32_bf16(a2_[f], CB[j], acc[4 + f][j], 0, 0, 0); \
        __builtin_amdgcn_s_setprio(0);                                             \
    }

    for (int kt = 0; kt < NT; kt += 2) {
        BODY(kt,     A0, B0, A1, B1);
        BODY(kt + 1, A1, B1, A0, B0);
    }
#undef BODY

    // ---- epilogue: C/D layout col=lane&15, row=(lane>>4)*4+reg ----
    int col0 = n0 + wn * 64 + (lane & 15);
    int row0 = m0 + wm * 128 + (lane >> 4) * 4;
#pragma unroll
    for (int f = 0; f < 8; ++f)
#pragma unroll
        for (int j = 0; j < 4; ++j) {
            f32x4 v = acc[f][j];
            int r = row0 + f * 16;
            int c = col0 + j * 16;
#pragma unroll
            for (int q = 0; q < 4; ++q)
                out[(size_t)(r + q) * N_TOTAL + c] = v[q];
        }
}

// ---------------------------------------------------------------------------
// Tier B: m97-structure GEMM, A reg-staged from f32 X (round-5 verified).
// ---------------------------------------------------------------------------
__global__ __launch_bounds__(256) void k_gemm2b(const float* __restrict__ X,
                                                const __hip_bfloat16* __restrict__ Wb,
                                                float* __restrict__ out) {
    __shared__ __align__(16) short As[128 * 32];
    __shared__ __align__(16) short Bs[128 * 32];
    int bid = blockIdx.x;
    int swz = (bid & 7) * 512 + (bid >> 3);
    int bn = swz & 31, bm = swz >> 5;
    int m0 = bm * 128, n0 = bn * 128;
    int t = threadIdx.x, lane = t & 63, wv = t >> 6;
    int wr = wv >> 1, wc = wv & 1;
    f32x4 acc[4][4];
#pragma unroll
    for (int i = 0; i < 4; ++i)
#pragma unroll
        for (int j = 0; j < 4; ++j) acc[i][j] = (f32x4)(0.0f);
    int arow = t >> 2, acol = (t & 3) * 8;
    const float* Agf0 = X + (size_t)(m0 + arow) * K_TOTAL + acol;
    const float* Agf1 = Agf0 + (size_t)64 * K_TOTAL;
    const __hip_bfloat16* Bg0 = Wb + (size_t)(n0 + arow) * K_TOTAL + acol;
    const __hip_bfloat16* Bg1 = Bg0 + (size_t)64 * K_TOTAL;
    float4 xa0 = *(const float4*)(Agf0), xa1 = *(const float4*)(Agf0 + 4);
    float4 xb0 = *(const float4*)(Agf1), xb1 = *(const float4*)(Agf1 + 4);
    for (int kt = 0; kt < NT; ++kt) {
        if (kt) __syncthreads();
        __hip_bfloat162 oa[4] = {
            __float22bfloat162_rn(make_float2(xa0.x, xa0.y)),
            __float22bfloat162_rn(make_float2(xa0.z, xa0.w)),
            __float22bfloat162_rn(make_float2(xa1.x, xa1.y)),
            __float22bfloat162_rn(make_float2(xa1.z, xa1.w))};
        __hip_bfloat162 ob[4] = {
            __float22bfloat162_rn(make_float2(xb0.x, xb0.y)),
            __float22bfloat162_rn(make_float2(xb0.z, xb0.w)),
            __float22bfloat162_rn(make_float2(xb1.x, xb1.y)),
            __float22bfloat162_rn(make_float2(xb1.z, xb1.w))};
        *(int4*)&As[t * 8] = *(int4*)&oa[0];
        *(int4*)&As[2048 + t * 8] = *(int4*)&ob[0];
        gload_lds16(Bg0 + kt * 32, &Bs[t * 8]);
        gload_lds16(Bg1 + kt * 32, &Bs[2048 + t * 8]);
        __syncthreads();
        if (kt < NT - 1) {
            int ko = (kt + 1) * 32;
            xa0 = *(const float4*)(Agf0 + ko);
            xa1 = *(const float4*)(Agf0 + ko + 4);
            xb0 = *(const float4*)(Agf1 + ko);
            xb1 = *(const float4*)(Agf1 + ko + 4);
        }
        bf16x8 a[4], b[4];
        int ro = (lane & 15) * 32 + (lane >> 4) * 8;
#pragma unroll
        for (int i = 0; i < 4; ++i)
            a[i] = *(const bf16x8*)&As[(wr * 64 + i * 16) * 32 + ro];
#pragma unroll
        for (int j = 0; j < 4; ++j)
            b[j] = *(const bf16x8*)&Bs[(wc * 64 + j * 16) * 32 + ro];
#pragma unroll
        for (int i = 0; i < 4; ++i)
#pragma unroll
            for (int j = 0; j < 4; ++j)
                acc[i][j] = __builtin_amdgcn_mfma_f32_16x16x32_bf16(a[i], b[j], acc[i][j], 0, 0, 0);
    }
    int col0 = n0 + wc * 64 + (lane & 15);
    int row0 = m0 + wr * 64 + (lane >> 4) * 4;
#pragma unroll
    for (int i = 0; i < 4; ++i)
#pragma unroll
        for (int j = 0; j < 4; ++j) {
            f32x4 v = acc[i][j];
            int r = row0 + i * 16, c = col0 + j * 16;
#pragma unroll
            for (int q = 0; q < 4; ++q)
                out[(size_t)(r + q) * N_TOTAL + c] = v[q];
        }
}

extern "C" void kernel_launch(void* const* d_in, const int* in_sizes, int n_in,
                              void* d_out, int out_size, void* d_ws, size_t ws_size,
                              hipStream_t stream) {
    const float* X = (const float*)d_in[0];
    const int* PW = (const int*)d_in[1];
    const float* SC = (const float*)d_in[2];
    float* OUT = (float*)d_out;

    const size_t needW = (size_t)N_TOTAL * K_TOTAL * 2;            // 33.5 MB
    const size_t needX = needW + (size_t)M_TOTAL * K_TOTAL * 2;    // +134 MB

    if (ws_size >= needX) {
        __hip_bfloat16* Wb = (__hip_bfloat16*)d_ws;
        __hip_bfloat16* Xb = (__hip_bfloat16*)((char*)d_ws + needW);
        k_convX<<<dim3(32768), dim3(256), 0, stream>>>(X, Xb);
        k_dequant<<<dim3(4096), dim3(256), 0, stream>>>(PW, SC, Wb);
        k_gemm4<<<dim3((M_TOTAL / 256) * (N_TOTAL / 256)), dim3(512), 0, stream>>>(Xb, Wb, OUT);
    } else if (ws_size >= needW) {
        __hip_bfloat16* Wb = (__hip_bfloat16*)d_ws;
        k_dequant<<<dim3(4096), dim3(256), 0, stream>>>(PW, SC, Wb);
        k_gemm2b<<<dim3((M_TOTAL / 128) * (N_TOTAL / 128)), dim3(256), 0, stream>>>(X, Wb, OUT);
    }
}

// Round 8
// 609.983 us; speedup vs baseline: 1.1054x; 1.1054x over previous
//
#include <hip/hip_runtime.h>
#include <hip/hip_bf16.h>
#include <stdint.h>

#define M_TOTAL 16384
#define N_TOTAL 4096
#define K_TOTAL 4096
#define NSTEP (K_TOTAL / 64)   // 64 K-steps of 64
#define NT32 (K_TOTAL / 32)

typedef __attribute__((ext_vector_type(8))) short bf16x8;
typedef __attribute__((ext_vector_type(4))) float f32x4;

__device__ __forceinline__ void gload_lds16(const void* g, void* l) {
    __builtin_amdgcn_global_load_lds(
        (const __attribute__((address_space(1))) uint32_t*)g,
        (__attribute__((address_space(3))) uint32_t*)l, 16, 0, 0);
}

// ---------------------------------------------------------------------------
// Kernel 0: X f32 -> bf16 (134 MB, L3-resident afterwards).
// ---------------------------------------------------------------------------
__global__ __launch_bounds__(256) void k_convX(const float* __restrict__ X,
                                               __hip_bfloat16* __restrict__ Xb) {
    size_t t = (size_t)blockIdx.x * 256 + threadIdx.x;
    const float* p = X + t * 8;
    float4 a = *(const float4*)p;
    float4 b = *(const float4*)(p + 4);
    __hip_bfloat162 o[4] = {
        __float22bfloat162_rn(make_float2(a.x, a.y)),
        __float22bfloat162_rn(make_float2(a.z, a.w)),
        __float22bfloat162_rn(make_float2(b.x, b.y)),
        __float22bfloat162_rn(make_float2(b.z, b.w))};
    *(int4*)(Xb + t * 8) = *(int4*)&o[0];
}

// ---------------------------------------------------------------------------
// Kernel 1: packed int4 -> bf16 W[N][K]. word j of row n: k=2j lo nibble,
// k=2j+1 hi nibble; codes 0..15 -> -8..7, scale[n][k/32] (f32).
// ---------------------------------------------------------------------------
__global__ __launch_bounds__(256) void k_dequant(const int* __restrict__ pw,
                                                 const float* __restrict__ sc,
                                                 __hip_bfloat16* __restrict__ W) {
    int t = blockIdx.x * 256 + threadIdx.x;
    int row = t >> 8;
    int w0 = (t & 255) << 3;
    const int* p = pw + (size_t)row * 2048 + w0;
    int4 q0 = *(const int4*)p;
    int4 q1 = *(const int4*)(p + 4);
    float s = sc[row * 128 + (w0 >> 4)];
    float ns8 = -8.0f * s;
    int w[8] = {q0.x, q0.y, q0.z, q0.w, q1.x, q1.y, q1.z, q1.w};
    __hip_bfloat162 o[8];
#pragma unroll
    for (int i = 0; i < 8; ++i) {
        float lo = fmaf((float)(w[i] & 15), s, ns8);
        float hi = fmaf((float)(w[i] >> 4), s, ns8);
        o[i] = __float22bfloat162_rn(make_float2(lo, hi));
    }
    __hip_bfloat16* dst = W + (size_t)row * 4096 + w0 * 2;
    *(int4*)dst = *(int4*)&o[0];
    *(int4*)(dst + 8) = *(int4*)&o[4];
}

// ---------------------------------------------------------------------------
// Kernel 2 (tier A): 8-phase template (m201 port). 256x256 tile, BK=64,
// 2 LDS double-buffers (128 KiB), 512 thr (8 waves 2Mx4N), per-wave 128x64.
// Phase = {ds_reads | stage 1 half-tile | barrier | 16 MFMA | barrier}.
// vmcnt(4) only at phases 4, 8.
//
// Stage schedule (iter computes steps s [buf0], s+1 [buf1]):
//   p1: A-h0(s+1)->buf1   p2: A-h1(s+1)->buf1     [buf1 A last read prev p7]
//   p3: B-h0(s+2)->buf0   p4: B-h1(s+2)->buf0     [buf0 B last read cur p2]
//   p5: A-h0(s+2)->buf0   p6: A-h1(s+2)->buf0     [buf0 A last read cur p3]
//   p7: B-h0(s+3)->buf1   p8: B-h1(s+3)->buf1     [buf1 B last read cur p6]
// vmcnt(4)@p4: waits prev-p7,p8 + cur-p1,p2 -> covers p5-p7 reads.
// vmcnt(4)@p8: waits cur-p3..p6 -> covers next p1-p3 reads. Invariant: 4 left.
//
// LDS layout (0-conflict, round-6 verified scheme @ BK=64): per 64-row x
// 128B block, 16B slot = (row%64>>3)*64 + chunk*8 + row%8; gload_lds dest
// linear in t, global source carries the permutation.
// ---------------------------------------------------------------------------
__global__ __launch_bounds__(512, 2) void k_gemm8(const __hip_bfloat16* __restrict__ Xb,
                                                  const __hip_bfloat16* __restrict__ Wb,
                                                  float* __restrict__ out) {
    __shared__ __align__(16) short L[2][2][2][8192];  // [buf][A/B][half][16KB]

    int bid = blockIdx.x;
    int swz = (bid & 7) * 128 + (bid >> 3);           // XCD-bijective (1024%8==0)
    int bn = swz & 15, bm = swz >> 4;
    int m0 = bm * 256, n0 = bn * 256;
    int t = threadIdx.x, lane = t & 63, wv = t >> 6;
    int wm = wv >> 2, wn = wv & 3, wnh = wn >> 1;

    // staging source: thread t -> row (t>>6)*8+(t&7) of a 64-row block, chunk (t>>3)&7
    int srow = (t >> 6) * 8 + (t & 7);
    int scol = ((t >> 3) & 7) * 8;
    const __hip_bfloat16* gA = Xb + (size_t)(m0 + srow) * K_TOTAL + scol;
    const __hip_bfloat16* gB = Wb + (size_t)(n0 + srow) * K_TOTAL + scol;

    auto stA = [&](int b, int h, int s_) {
        gload_lds16(gA + (size_t)(h * 128) * K_TOTAL + s_ * 64, &L[b][0][h][t * 8]);
        gload_lds16(gA + (size_t)(h * 128 + 64) * K_TOTAL + s_ * 64, &L[b][0][h][4096 + t * 8]);
    };
    auto stB = [&](int b, int h, int s_) {
        gload_lds16(gB + (size_t)(h * 128) * K_TOTAL + s_ * 64, &L[b][1][h][t * 8]);
        gload_lds16(gB + (size_t)(h * 128 + 64) * K_TOTAL + s_ * 64, &L[b][1][h][4096 + t * 8]);
    };

    // frag-read lane offsets (shorts): row rr=R+(lane&15), chunk c=kk*4+(lane>>4)
    // off = (rr>>6)*4096 + ((rr>>3)&7)*512 + (c*8 + (rr&7))*8
    const int lo0 = ((lane & 15) >> 3) * 512 + ((lane >> 4) * 8 + (lane & 7)) * 8;
    const int lo1 = lo0 + 256;
    const int cbase = (wn & 1) * 4096;

    f32x4 acc[8][4];
#pragma unroll
    for (int f = 0; f < 8; ++f)
#pragma unroll
        for (int j = 0; j < 4; ++j) acc[f][j] = (f32x4)(0.0f);

    bf16x8 Af[8], Bq01[4], Bq23[4];

#define RD_A(rfb) { _Pragma("unroll") for (int rf = 0; rf < 4; ++rf) { \
        const int rb = (((rfb) + rf) >> 2) * 4096 + (((rfb) + rf) & 3) * 1024; \
        Af[rf * 2]     = *(const bf16x8*)&LA[rb + lo0]; \
        Af[rf * 2 + 1] = *(const bf16x8*)&LA[rb + lo1]; } }
#define RD_B(dst, cfb) { _Pragma("unroll") for (int cf = 0; cf < 2; ++cf) { \
        const int cb = cbase + ((cfb) + cf) * 1024; \
        dst[cf * 2]     = *(const bf16x8*)&LB[cb + lo0]; \
        dst[cf * 2 + 1] = *(const bf16x8*)&LB[cb + lo1]; } }
#define MM16(rfb, Bv, cfb) { _Pragma("unroll") for (int kk = 0; kk < 2; ++kk) \
        _Pragma("unroll") for (int rf = 0; rf < 4; ++rf) \
        _Pragma("unroll") for (int cf = 0; cf < 2; ++cf) \
            acc[(rfb) + rf][(cfb) + cf] = __builtin_amdgcn_mfma_f32_16x16x32_bf16( \
                Af[rf * 2 + kk], Bv[cf * 2 + kk], acc[(rfb) + rf][(cfb) + cf], 0, 0, 0); }
#define BAR __builtin_amdgcn_s_barrier()
#define PRI(x) __builtin_amdgcn_s_setprio(x)

    auto vmw = [&](bool g) {
        if (g) { asm volatile("s_waitcnt vmcnt(4)" ::: "memory"); }
        else   { asm volatile("s_waitcnt vmcnt(0)" ::: "memory"); }
        __builtin_amdgcn_sched_barrier(0);
    };

    // ---- prologue: B(0), A(0), B(1); leave B(1)'s 4 loads outstanding ----
    stB(0, 0, 0); stB(0, 1, 0);
    stA(0, 0, 0); stA(0, 1, 0);
    stB(1, 0, 1); stB(1, 1, 1);
    asm volatile("s_waitcnt vmcnt(4)" ::: "memory");
    __builtin_amdgcn_sched_barrier(0);
    BAR;

    for (int i = 0; i < NSTEP / 2; ++i) {
        const int s = 2 * i;
        const bool g = (s + 2 < NSTEP);
        // ======== K-step s (buf 0) ========
        {
            const short* LA = &L[0][0][wm][0];
            const short* LB = &L[0][1][wnh][0];
            // p1: rf0-3 x cf0-1
            RD_A(0) RD_B(Bq01, 0)
            stA(1, 0, s + 1);
            BAR; PRI(1); MM16(0, Bq01, 0) PRI(0); BAR;
            // p2: rf0-3 x cf2-3
            RD_B(Bq23, 2)
            stA(1, 1, s + 1);
            BAR; PRI(1); MM16(0, Bq23, 2) PRI(0); BAR;
            // p3: rf4-7 x cf0-1
            RD_A(4)
            if (g) stB(0, 0, s + 2);
            BAR; PRI(1); MM16(4, Bq01, 0) PRI(0); BAR;
            // p4: rf4-7 x cf2-3
            if (g) stB(0, 1, s + 2);
            BAR; PRI(1); MM16(4, Bq23, 2) PRI(0);
            vmw(g);
            BAR;
        }
        // ======== K-step s+1 (buf 1) ========
        {
            const short* LA = &L[1][0][wm][0];
            const short* LB = &L[1][1][wnh][0];
            // p5
            RD_A(0) RD_B(Bq01, 0)
            if (g) stA(0, 0, s + 2);
            BAR; PRI(1); MM16(0, Bq01, 0) PRI(0); BAR;
            // p6
            RD_B(Bq23, 2)
            if (g) stA(0, 1, s + 2);
            BAR; PRI(1); MM16(0, Bq23, 2) PRI(0); BAR;
            // p7
            RD_A(4)
            if (g) stB(1, 0, s + 3);
            BAR; PRI(1); MM16(4, Bq01, 0) PRI(0); BAR;
            // p8
            if (g) stB(1, 1, s + 3);
            BAR; PRI(1); MM16(4, Bq23, 2) PRI(0);
            vmw(g);
            BAR;
        }
    }
#undef RD_A
#undef RD_B
#undef MM16
#undef BAR
#undef PRI

    // ---- epilogue: C/D layout col=lane&15, row=(lane>>4)*4+reg ----
    int col0 = n0 + wn * 64 + (lane & 15);
    int row0 = m0 + wm * 128 + (lane >> 4) * 4;
#pragma unroll
    for (int f = 0; f < 8; ++f)
#pragma unroll
        for (int j = 0; j < 4; ++j) {
            f32x4 v = acc[f][j];
            int r = row0 + f * 16;
            int c = col0 + j * 16;
#pragma unroll
            for (int q = 0; q < 4; ++q)
                out[(size_t)(r + q) * N_TOTAL + c] = v[q];
        }
}

// ---------------------------------------------------------------------------
// Tier B: m97-structure GEMM, A reg-staged from f32 X (round-5 verified).
// ---------------------------------------------------------------------------
__global__ __launch_bounds__(256) void k_gemm2b(const float* __restrict__ X,
                                                const __hip_bfloat16* __restrict__ Wb,
                                                float* __restrict__ out) {
    __shared__ __align__(16) short As[128 * 32];
    __shared__ __align__(16) short Bs[128 * 32];
    int bid = blockIdx.x;
    int swz = (bid & 7) * 512 + (bid >> 3);
    int bn = swz & 31, bm = swz >> 5;
    int m0 = bm * 128, n0 = bn * 128;
    int t = threadIdx.x, lane = t & 63, wv = t >> 6;
    int wr = wv >> 1, wc = wv & 1;
    f32x4 acc[4][4];
#pragma unroll
    for (int i = 0; i < 4; ++i)
#pragma unroll
        for (int j = 0; j < 4; ++j) acc[i][j] = (f32x4)(0.0f);
    int arow = t >> 2, acol = (t & 3) * 8;
    const float* Agf0 = X + (size_t)(m0 + arow) * K_TOTAL + acol;
    const float* Agf1 = Agf0 + (size_t)64 * K_TOTAL;
    const __hip_bfloat16* Bg0 = Wb + (size_t)(n0 + arow) * K_TOTAL + acol;
    const __hip_bfloat16* Bg1 = Bg0 + (size_t)64 * K_TOTAL;
    float4 xa0 = *(const float4*)(Agf0), xa1 = *(const float4*)(Agf0 + 4);
    float4 xb0 = *(const float4*)(Agf1), xb1 = *(const float4*)(Agf1 + 4);
    for (int kt = 0; kt < NT32; ++kt) {
        if (kt) __syncthreads();
        __hip_bfloat162 oa[4] = {
            __float22bfloat162_rn(make_float2(xa0.x, xa0.y)),
            __float22bfloat162_rn(make_float2(xa0.z, xa0.w)),
            __float22bfloat162_rn(make_float2(xa1.x, xa1.y)),
            __float22bfloat162_rn(make_float2(xa1.z, xa1.w))};
        __hip_bfloat162 ob[4] = {
            __float22bfloat162_rn(make_float2(xb0.x, xb0.y)),
            __float22bfloat162_rn(make_float2(xb0.z, xb0.w)),
            __float22bfloat162_rn(make_float2(xb1.x, xb1.y)),
            __float22bfloat162_rn(make_float2(xb1.z, xb1.w))};
        *(int4*)&As[t * 8] = *(int4*)&oa[0];
        *(int4*)&As[2048 + t * 8] = *(int4*)&ob[0];
        gload_lds16(Bg0 + kt * 32, &Bs[t * 8]);
        gload_lds16(Bg1 + kt * 32, &Bs[2048 + t * 8]);
        __syncthreads();
        if (kt < NT32 - 1) {
            int ko = (kt + 1) * 32;
            xa0 = *(const float4*)(Agf0 + ko);
            xa1 = *(const float4*)(Agf0 + ko + 4);
            xb0 = *(const float4*)(Agf1 + ko);
            xb1 = *(const float4*)(Agf1 + ko + 4);
        }
        bf16x8 a[4], b[4];
        int ro = (lane & 15) * 32 + (lane >> 4) * 8;
#pragma unroll
        for (int i = 0; i < 4; ++i)
            a[i] = *(const bf16x8*)&As[(wr * 64 + i * 16) * 32 + ro];
#pragma unroll
        for (int j = 0; j < 4; ++j)
            b[j] = *(const bf16x8*)&Bs[(wc * 64 + j * 16) * 32 + ro];
#pragma unroll
        for (int i = 0; i < 4; ++i)
#pragma unroll
            for (int j = 0; j < 4; ++j)
                acc[i][j] = __builtin_amdgcn_mfma_f32_16x16x32_bf16(a[i], b[j], acc[i][j], 0, 0, 0);
    }
    int col0 = n0 + wc * 64 + (lane & 15);
    int row0 = m0 + wr * 64 + (lane >> 4) * 4;
#pragma unroll
    for (int i = 0; i < 4; ++i)
#pragma unroll
        for (int j = 0; j < 4; ++j) {
            f32x4 v = acc[i][j];
            int r = row0 + i * 16, c = col0 + j * 16;
#pragma unroll
            for (int q = 0; q < 4; ++q)
                out[(size_t)(r + q) * N_TOTAL + c] = v[q];
        }
}

extern "C" void kernel_launch(void* const* d_in, const int* in_sizes, int n_in,
                              void* d_out, int out_size, void* d_ws, size_t ws_size,
                              hipStream_t stream) {
    const float* X = (const float*)d_in[0];
    const int* PW = (const int*)d_in[1];
    const float* SC = (const float*)d_in[2];
    float* OUT = (float*)d_out;

    const size_t needW = (size_t)N_TOTAL * K_TOTAL * 2;            // 33.5 MB
    const size_t needX = needW + (size_t)M_TOTAL * K_TOTAL * 2;    // +134 MB

    if (ws_size >= needX) {
        __hip_bfloat16* Wb = (__hip_bfloat16*)d_ws;
        __hip_bfloat16* Xb = (__hip_bfloat16*)((char*)d_ws + needW);
        k_convX<<<dim3(32768), dim3(256), 0, stream>>>(X, Xb);
        k_dequant<<<dim3(4096), dim3(256), 0, stream>>>(PW, SC, Wb);
        k_gemm8<<<dim3((M_TOTAL / 256) * (N_TOTAL / 256)), dim3(512), 0, stream>>>(Xb, Wb, OUT);
    } else if (ws_size >= needW) {
        __hip_bfloat16* Wb = (__hip_bfloat16*)d_ws;
        k_dequant<<<dim3(4096), dim3(256), 0, stream>>>(PW, SC, Wb);
        k_gemm2b<<<dim3((M_TOTAL / 128) * (N_TOTAL / 128)), dim3(256), 0, stream>>>(X, Wb, OUT);
    }
}